// Round 9
// baseline (119.521 us; speedup 1.0000x reference)
//
#include <hip/hip_runtime.h>

// B=2, N=4, C=256, H=W=128, J=2, heads=8, hd=32, T=1024
// Algebra: idwt linear + Haar orthonormal =>
//   out_full = query + upsample4(0.25*(mb - qll))
//   sum(out) = 4*sum(mb); sum(out^2) = sum(query^2) + sum(mb^2) - sum(qll^2)
// kv-DWT is fused into the K/V conv (kvll never materialized; kvm read once).
// GN stats from register-level partials (dwt partial + conv_pm pm_part).
// ws (float units): qll(bf16) 262144 | qbp(u32) 262144 | kbp(u32) 1048576 |
//   vb(bf16) 1048576 | aop(u32) 1048576 | mb 524288 | partial 2048 | pm 2048

typedef float f32x16 __attribute__((ext_vector_type(16)));
typedef short s16x8 __attribute__((ext_vector_type(8)));

static __device__ __forceinline__ unsigned f2bf_bits(float x) {
  unsigned u = __float_as_uint(x);
  return (u + 0x7fffu + ((u >> 16) & 1u)) >> 16;
}
static __device__ __forceinline__ unsigned pack2(float a, float b) {
  return f2bf_bits(a) | (f2bf_bits(b) << 16);
}
static __device__ __forceinline__ float bflo(unsigned u) {
  return __uint_as_float(u << 16);
}
// XOR-swizzle for 128B-row LDS tiles: slot bits [6:4] ^= row bits [9:7]
static __device__ __forceinline__ int swz(int byte) {
  return byte ^ (((byte >> 7) & 7) << 4);
}

// --- conv staging helpers ---------------------------------------------
static __device__ __forceinline__ void stage_w(const float* __restrict__ Wm,
    char* ldsA, int o0, int k0, int oA, int kqA, float sc) {
  const float* wp = Wm + (size_t)(o0 + oA) * 256 + k0 + kqA;
  float4 w0 = *reinterpret_cast<const float4*>(wp);
  float4 w1 = *reinterpret_cast<const float4*>(wp + 4);
  float4 w2 = *reinterpret_cast<const float4*>(wp + 8);
  float4 w3 = *reinterpret_cast<const float4*>(wp + 12);
  union { s16x8 v; unsigned u[4]; } a0, a1;
  a0.u[0] = pack2(sc * w0.x, sc * w0.y); a0.u[1] = pack2(sc * w0.z, sc * w0.w);
  a0.u[2] = pack2(sc * w1.x, sc * w1.y); a0.u[3] = pack2(sc * w1.z, sc * w1.w);
  a1.u[0] = pack2(sc * w2.x, sc * w2.y); a1.u[1] = pack2(sc * w2.z, sc * w2.w);
  a1.u[2] = pack2(sc * w3.x, sc * w3.y); a1.u[3] = pack2(sc * w3.z, sc * w3.w);
  int byte0 = oA * 128 + kqA * 2;
  *reinterpret_cast<s16x8*>(ldsA + swz(byte0))      = a0.v;
  *reinterpret_cast<s16x8*>(ldsA + swz(byte0 + 16)) = a1.v;
}

// X is bf16 [c][t] (ushort); pack k-pairs into u32.
static __device__ __forceinline__ void stage_x_bf(const unsigned short* __restrict__ Xp,
    char* ldsB, int k0, int t0, int tB, int kg0) {
#pragma unroll
  for (int rep = 0; rep < 2; ++rep) {
    int kg = kg0 + rep * 4;
    const unsigned short* xp = Xp + (size_t)(k0 + kg * 8) * 1024 + t0 + tB;
    union { s16x8 v; unsigned u[4]; } b;
#pragma unroll
    for (int e2 = 0; e2 < 4; ++e2) {
      unsigned lo = xp[(size_t)(2 * e2) * 1024];
      unsigned hi2 = xp[(size_t)(2 * e2 + 1) * 1024];
      b.u[e2] = lo | (hi2 << 16);
    }
    *reinterpret_cast<s16x8*>(ldsB + swz(tB * 128 + kg * 16)) = b.v;
  }
}

// ---------------------------------------------------------------------------
// K1: fused kernel.
//   blocks [0,256): K/V conv with on-the-fly Haar-LL staging from kvm.
//     block = (jj, tt): 256 o x 32 t. LDS: X 4KB + Wk 16KB + Wv 16KB.
//   blocks [256,2304): query DWT -> qll (bf16) + partial (sum q^2 - sum qll^2).
// ---------------------------------------------------------------------------
__global__ __launch_bounds__(256) void kvconv_qdwt_kernel(
    const float* __restrict__ kvm, const float* __restrict__ query,
    const float* __restrict__ Wk, const float* __restrict__ bk,
    const float* __restrict__ Wv, const float* __restrict__ bv,
    unsigned* __restrict__ kbp, unsigned short* __restrict__ vb,
    unsigned short* __restrict__ qll, float* __restrict__ partial) {
  __shared__ __align__(16) char lds[36864];
  const int tid = threadIdx.x;
  const int bid = blockIdx.x;

  if (bid >= 256) {
    // ---- query DWT ----
    int idx = (bid - 256) * 256 + tid;     // < 524288
    int bc = idx >> 10;
    int t  = idx & 1023;
    int i = t >> 5, j = t & 31;
    const float* xp = query + (size_t)bc * 16384;
    float s = 0.f, e = 0.f;
#pragma unroll
    for (int rr = 0; rr < 4; ++rr) {
      float4 v = *reinterpret_cast<const float4*>(xp + (4 * i + rr) * 128 + 4 * j);
      s += (v.x + v.y) + (v.z + v.w);
      e += (v.x * v.x + v.y * v.y) + (v.z * v.z + v.w * v.w);
    }
    unsigned bits = f2bf_bits(0.25f * s);
    qll[idx] = (unsigned short)bits;
    float qv = __uint_as_float(bits << 16);
    e -= qv * qv;
#pragma unroll
    for (int o = 32; o > 0; o >>= 1) e += __shfl_xor(e, o);
    float* red = reinterpret_cast<float*>(lds);
    if ((tid & 63) == 0) red[tid >> 6] = e;
    __syncthreads();
    if (tid == 0) partial[bid - 256] = (red[0] + red[1]) + (red[2] + red[3]);
    return;
  }

  // ---- fused kv conv ----
  const int jj = bid >> 5;        // 0..7
  const int tt = bid & 31;        // t-tile (i value): t = tt*32 + j2
  const int n = jj >> 1, b = jj & 1;
  const float* kvbase = kvm + (size_t)(b * 4 + n) * 256 * 16384;

  char* ldsX  = lds;              // 4 KB  [t(32)][k(64) bf16] swizzled rows
  char* ldsWk = lds + 4096;       // 16 KB [o-local(128)][k] (2x 8KB chunks)
  char* ldsWv = lds + 20480;      // 16 KB

  const int w  = tid >> 6;
  const int hi = (tid >> 5) & 1;
  const int ln = tid & 31;

  f32x16 acck0, acck1, accv0, accv1;
#pragma unroll
  for (int r = 0; r < 16; ++r) { acck0[r] = 0.f; acck1[r] = 0.f; accv0[r] = 0.f; accv1[r] = 0.f; }

  const int cp8 = tid >> 5;       // 0..7
  const int j2  = tid & 31;
  const int oA  = tid >> 2;       // for stage_w
  const int kqA = (tid & 3) * 16;

  for (int kk = 0; kk < 4; ++kk) {
    const int k0 = kk * 64;
    // --- stage X: Haar LL of kvm, 64 ch x 32 t, packed bf16 pairs over k ---
#pragma unroll
    for (int p = 0; p < 4; ++p) {
      int cpe = p * 8 + cp8;                 // c-pair 0..31
      const float* x0 = kvbase + (size_t)(k0 + 2 * cpe) * 16384 + (4 * tt) * 128 + 4 * j2;
      float s0 = 0.f, s1 = 0.f;
#pragma unroll
      for (int rr = 0; rr < 4; ++rr) {
        float4 v = *reinterpret_cast<const float4*>(x0 + rr * 128);
        s0 += (v.x + v.y) + (v.z + v.w);
      }
      const float* x1 = x0 + 16384;
#pragma unroll
      for (int rr = 0; rr < 4; ++rr) {
        float4 v = *reinterpret_cast<const float4*>(x1 + rr * 128);
        s1 += (v.x + v.y) + (v.z + v.w);
      }
      *reinterpret_cast<unsigned*>(ldsX + swz(j2 * 128 + cpe * 4)) =
          pack2(0.25f * s0, 0.25f * s1);
    }
    // --- two o-halves: stage W, MFMA ---
#pragma unroll
    for (int oh = 0; oh < 2; ++oh) {
      stage_w(Wk, ldsWk,        oh * 128,      k0, oA, kqA, 1.f);
      stage_w(Wk, ldsWk + 8192, oh * 128 + 64, k0, oA, kqA, 1.f);
      stage_w(Wv, ldsWv,        oh * 128,      k0, oA, kqA, 1.f);
      stage_w(Wv, ldsWv + 8192, oh * 128 + 64, k0, oA, kqA, 1.f);
      __syncthreads();
      char* wkb = ldsWk + (w >> 1) * 8192;
      char* wvb = ldsWv + (w >> 1) * 8192;
      int rowb = ((w & 1) * 32 + ln) * 128;
#pragma unroll
      for (int ks = 0; ks < 64; ks += 16) {
        s16x8 bfx = *reinterpret_cast<const s16x8*>(ldsX + swz(ln * 128 + ks * 2 + hi * 16));
        s16x8 afk = *reinterpret_cast<const s16x8*>(wkb + swz(rowb + ks * 2 + hi * 16));
        s16x8 afv = *reinterpret_cast<const s16x8*>(wvb + swz(rowb + ks * 2 + hi * 16));
        if (oh == 0) {
          acck0 = __builtin_amdgcn_mfma_f32_32x32x16_bf16(afk, bfx, acck0, 0, 0, 0);
          accv0 = __builtin_amdgcn_mfma_f32_32x32x16_bf16(afv, bfx, accv0, 0, 0, 0);
        } else {
          acck1 = __builtin_amdgcn_mfma_f32_32x32x16_bf16(afk, bfx, acck1, 0, 0, 0);
          accv1 = __builtin_amdgcn_mfma_f32_32x32x16_bf16(afv, bfx, accv1, 0, 0, 0);
        }
      }
      __syncthreads();
    }
  }

  // --- epilogue: o = oh*128 + w*32 + (r&3)+8*(r>>2)+4*hi; t = tt*32 + ln ---
  unsigned* Yk = kbp + (size_t)jj * 131072;
  unsigned short* Yv = vb + (size_t)jj * 262144;
  const int tg = tt * 32 + ln;
#pragma unroll
  for (int oh = 0; oh < 2; ++oh) {
#pragma unroll
    for (int r = 0; r < 16; r += 2) {
      int o = oh * 128 + w * 32 + (r & 3) + 8 * (r >> 2) + 4 * hi;
      float k0v = (oh ? acck1[r] : acck0[r]) + bk[o];
      float k1v = (oh ? acck1[r + 1] : acck0[r + 1]) + bk[o + 1];
      Yk[(size_t)(o >> 1) * 1024 + tg] = pack2(k0v, k1v);
      float v0v = (oh ? accv1[r] : accv0[r]) + bv[o];
      float v1v = (oh ? accv1[r + 1] : accv0[r + 1]) + bv[o + 1];
      Yv[(size_t)o * 1024 + tg]       = (unsigned short)f2bf_bits(v0v);
      Yv[(size_t)(o + 1) * 1024 + tg] = (unsigned short)f2bf_bits(v1v);
    }
  }
}

// ---------------------------------------------------------------------------
// K2: Q conv (64o x 64t tiles, grid (16,4,2)); scale folded; paired output.
// ---------------------------------------------------------------------------
__global__ __launch_bounds__(256) void conv_q_kernel(
    const unsigned short* __restrict__ qll,
    const float* __restrict__ Wq, const float* __restrict__ bq,
    unsigned* __restrict__ qbp) {
  const int tid = threadIdx.x;
  const int hi = (tid >> 5) & 1;
  const int ln = tid & 31;
  const int w = tid >> 6;
  const int o_off = (w >> 1) * 32;
  const int t_off = (w & 1) * 32;
  const int t0 = blockIdx.x * 64;
  const int o0 = blockIdx.y * 64;
  const int z = blockIdx.z;

  __shared__ __align__(16) char lds[16384];
  char* ldsA = lds;
  char* ldsB = lds + 8192;

  const int oA = tid >> 2;
  const int kqA = (tid & 3) * 16;
  const int tB = tid & 63;
  const int kg0 = tid >> 6;

  const float S = 0.17677669529663687f;   // hd^-0.5 folded into Wq, bq
  const unsigned short* Xp = qll + (size_t)z * 262144;
  f32x16 acc;
#pragma unroll
  for (int r = 0; r < 16; ++r) acc[r] = 0.f;
  for (int kk = 0; kk < 4; ++kk) {
    const int k0 = kk * 64;
    stage_w(Wq, ldsA, o0, k0, oA, kqA, S);
    stage_x_bf(Xp, ldsB, k0, t0, tB, kg0);
    __syncthreads();
#pragma unroll
    for (int ks = 0; ks < 64; ks += 16) {
      s16x8 af = *reinterpret_cast<const s16x8*>(ldsA + swz((o_off + ln) * 128 + ks * 2 + hi * 16));
      s16x8 bf = *reinterpret_cast<const s16x8*>(ldsB + swz((t_off + ln) * 128 + ks * 2 + hi * 16));
      acc = __builtin_amdgcn_mfma_f32_32x32x16_bf16(af, bf, acc, 0, 0, 0);
    }
    __syncthreads();
  }
  unsigned* Yp = qbp + (size_t)z * 131072;
#pragma unroll
  for (int r = 0; r < 16; r += 2) {
    int o = o_off + (r & 3) + 8 * (r >> 2) + 4 * hi;    // even
    float b0 = S * bq[o0 + o], b1 = S * bq[o0 + o + 1];
    Yp[(size_t)((o0 + o) >> 1) * 1024 + t0 + t_off + ln] =
        pack2(acc[r] + b0, acc[r + 1] + b1);
  }
}

// ---------------------------------------------------------------------------
// MFMA flash attention (unchanged; pre-paired bf16 inputs).
// ---------------------------------------------------------------------------
__global__ __launch_bounds__(256) void attn_mfma_kernel(
    const unsigned* __restrict__ qbp, const unsigned* __restrict__ kbp,
    const unsigned short* __restrict__ vb, unsigned* __restrict__ aop) {
  const int tid = threadIdx.x;
  const int w   = tid >> 6;
  const int hi  = (tid >> 5) & 1;
  const int ln  = tid & 31;
  const int jh  = blockIdx.x >> 3;
  const int qg  = blockIdx.x & 7;
  const int qbase = (qg * 4 + w) * 32;
  const int j = jh >> 3, h = jh & 7;
  const unsigned* qp = qbp + (size_t)((j & 1) * 8 + h) * 16384;
  const unsigned* kp = kbp + (size_t)jh * 16384;
  const unsigned short* vp = vb + (size_t)jh * 32768;

  __shared__ unsigned KpL[2][544];
  __shared__ unsigned VpL[2][544];
  __shared__ float tileT[4][1056];

  const int sdp = tid >> 5;   // 0..7
  const int st  = tid & 31;
  const int svd = tid >> 4;   // 0..15
  const int svt = tid & 15;

  s16x8 Qf[2];
#pragma unroll
  for (int c = 0; c < 2; ++c) {
    union { s16x8 v; unsigned u[4]; } u;
#pragma unroll
    for (int e2 = 0; e2 < 4; ++e2)
      u.u[e2] = qp[(size_t)(c * 8 + hi * 4 + e2) * 1024 + qbase + ln];
    Qf[c] = u.v;
  }

  f32x16 acc;
#pragma unroll
  for (int r = 0; r < 16; ++r) acc[r] = 0.f;
  float m = -1e30f, lsum = 0.f;

  {
    KpL[0][st * 17 + sdp]     = kp[(size_t)sdp * 1024 + st];
    KpL[0][st * 17 + sdp + 8] = kp[(size_t)(sdp + 8) * 1024 + st];
    VpL[0][svd * 17 + svt] =
        *reinterpret_cast<const unsigned*>(vp + (size_t)svd * 1024 + 2 * svt);
    VpL[0][(svd + 16) * 17 + svt] =
        *reinterpret_cast<const unsigned*>(vp + (size_t)(svd + 16) * 1024 + 2 * svt);
  }
  __syncthreads();

  for (int tile = 0; tile < 32; ++tile) {
    const int cur = tile & 1;
    unsigned nk0 = 0, nk1 = 0, nv0 = 0, nv1 = 0;
    if (tile < 31) {
      const int kn = (tile + 1) * 32;
      nk0 = kp[(size_t)sdp * 1024 + kn + st];
      nk1 = kp[(size_t)(sdp + 8) * 1024 + kn + st];
      nv0 = *reinterpret_cast<const unsigned*>(vp + (size_t)svd * 1024 + kn + 2 * svt);
      nv1 = *reinterpret_cast<const unsigned*>(vp + (size_t)(svd + 16) * 1024 + kn + 2 * svt);
    }

    s16x8 Kf[2];
#pragma unroll
    for (int c = 0; c < 2; ++c) {
      union { s16x8 v; unsigned u[4]; } u;
#pragma unroll
      for (int e = 0; e < 4; ++e)
        u.u[e] = KpL[cur][ln * 17 + c * 8 + hi * 4 + e];
      Kf[c] = u.v;
    }
    f32x16 S;
#pragma unroll
    for (int r = 0; r < 16; ++r) S[r] = 0.f;
    S = __builtin_amdgcn_mfma_f32_32x32x16_bf16(Kf[0], Qf[0], S, 0, 0, 0);
    S = __builtin_amdgcn_mfma_f32_32x32x16_bf16(Kf[1], Qf[1], S, 0, 0, 0);

    float tmax = S[0];
#pragma unroll
    for (int r = 1; r < 16; ++r) tmax = fmaxf(tmax, S[r]);
    tmax = fmaxf(tmax, __shfl_xor(tmax, 32));
    if (__any(tmax > m + 6.f)) {
      float nm = fmaxf(m, tmax);
      float f  = __expf(m - nm);
      m = nm;
      lsum *= f;
      int fi = __float_as_int(f);
#pragma unroll
      for (int r = 0; r < 16; ++r) {
        int row = (r & 3) + 8 * (r >> 2) + 4 * hi;
        float fr = __int_as_float(__builtin_amdgcn_ds_bpermute(row * 4, fi));
        acc[r] *= fr;
      }
    }
    float p[16];
#pragma unroll
    for (int r = 0; r < 16; ++r) {
      p[r] = __expf(S[r] - m);
      lsum += p[r];
    }
    unsigned P[8];
#pragma unroll
    for (int i = 0; i < 8; ++i) P[i] = pack2(p[2 * i], p[2 * i + 1]);

#pragma unroll
    for (int c = 0; c < 2; ++c) {
      unsigned p0 = P[4 * c + 0], p1 = P[4 * c + 1];
      unsigned p2 = P[4 * c + 2], p3 = P[4 * c + 3];
      unsigned s0 = (unsigned)__shfl_xor((int)p0, 32);
      unsigned s1 = (unsigned)__shfl_xor((int)p1, 32);
      unsigned s2 = (unsigned)__shfl_xor((int)p2, 32);
      unsigned s3 = (unsigned)__shfl_xor((int)p3, 32);
      union { s16x8 v; unsigned u[4]; } pa;
      pa.u[0] = hi ? s2 : p0;
      pa.u[1] = hi ? s3 : p1;
      pa.u[2] = hi ? p2 : s0;
      pa.u[3] = hi ? p3 : s1;
      union { s16x8 v; unsigned u[4]; } vf;
#pragma unroll
      for (int e = 0; e < 4; ++e)
        vf.u[e] = VpL[cur][ln * 17 + c * 8 + hi * 4 + e];
      acc = __builtin_amdgcn_mfma_f32_32x32x16_bf16(pa.v, vf.v, acc, 0, 0, 0);
    }

    if (tile < 31) {
      const int nxt = cur ^ 1;
      KpL[nxt][st * 17 + sdp]     = nk0;
      KpL[nxt][st * 17 + sdp + 8] = nk1;
      VpL[nxt][svd * 17 + svt]        = nv0;
      VpL[nxt][(svd + 16) * 17 + svt] = nv1;
    }
    __syncthreads();
  }

  float ltot = lsum + __shfl_xor(lsum, 32);
  float inv  = 1.f / ltot;

  float* tw = tileT[w];
#pragma unroll
  for (int r = 0; r < 16; ++r) {
    int row = (r & 3) + 8 * (r >> 2) + 4 * hi;
    tw[row * 33 + ln] = acc[r];
  }
  __syncthreads();
  unsigned* aw = aop + (size_t)jh * 16384;
#pragma unroll
  for (int pass = 0; pass < 8; ++pass) {
    int dp = pass * 2 + hi;
    float v0 = tw[ln * 33 + 2 * dp] * inv;
    float v1 = tw[ln * 33 + 2 * dp + 1] * inv;
    aw[(size_t)dp * 1024 + qbase + ln] = pack2(v0, v1);
  }
}

// A is paired-bf16 [cpair][t] (u32); mean over 4 j-slices (stride 131072 u32).
static __device__ __forceinline__ void stage_x_m4p(const unsigned* __restrict__ Ap,
    char* ldsB, int k0, int t0, int tB, int kg0) {
#pragma unroll
  for (int rep = 0; rep < 2; ++rep) {
    int kg = kg0 + rep * 4;
    const unsigned* xp = Ap + (size_t)(k0 / 2 + kg * 4) * 1024 + t0 + tB;
    union { s16x8 v; unsigned u[4]; } b;
#pragma unroll
    for (int e2 = 0; e2 < 4; ++e2) {
      unsigned a0 = xp[(size_t)e2 * 1024];
      unsigned a1 = xp[(size_t)e2 * 1024 + 131072];
      unsigned a2 = xp[(size_t)e2 * 1024 + 262144];
      unsigned a3 = xp[(size_t)e2 * 1024 + 393216];
      float lo = 0.25f * ((bflo(a0) + bflo(a1)) + (bflo(a2) + bflo(a3)));
      float hi2 = 0.25f * ((__uint_as_float(a0 & 0xffff0000u) + __uint_as_float(a1 & 0xffff0000u)) +
                           (__uint_as_float(a2 & 0xffff0000u) + __uint_as_float(a3 & 0xffff0000u)));
      b.u[e2] = pack2(lo, hi2);
    }
    *reinterpret_cast<s16x8*>(ldsB + swz(tB * 128 + kg * 16)) = b.v;
  }
}

// ---------------------------------------------------------------------------
// P-conv with fused mean over 4 j-slices; emits per-(group, t-tile) GN
// partials (sum, sum^2) from registers.
// ---------------------------------------------------------------------------
__global__ __launch_bounds__(256) void conv_pm_kernel(const unsigned* __restrict__ aop,
    const float* __restrict__ Wm, const float* __restrict__ bias,
    float* __restrict__ Y, float* __restrict__ pm_part) {
  const int tid = threadIdx.x;
  const int hi = (tid >> 5) & 1;
  const int ln = tid & 31;
  const int w = tid >> 6;
  const int o_off = (w >> 1) * 32;
  const int t_off = (w & 1) * 32;
  const int t0 = blockIdx.x * 64;
  const int o0 = blockIdx.y * 64;
  const int bp = blockIdx.z;
  const unsigned* Ap = aop + (size_t)bp * 524288;

  __shared__ __align__(16) char lds[16384];
  char* ldsA = lds;
  char* ldsB = lds + 8192;

  f32x16 acc;
#pragma unroll
  for (int r = 0; r < 16; ++r) acc[r] = 0.f;

  const int oA = tid >> 2;
  const int kqA = (tid & 3) * 16;
  const int tB = tid & 63;
  const int kg0 = tid >> 6;

  for (int kk = 0; kk < 4; ++kk) {
    const int k0 = kk * 64;
    stage_w(Wm, ldsA, o0, k0, oA, kqA, 1.f);
    stage_x_m4p(Ap, ldsB, k0, t0, tB, kg0);
    __syncthreads();
#pragma unroll
    for (int ks = 0; ks < 64; ks += 16) {
      s16x8 af = *reinterpret_cast<const s16x8*>(ldsA + swz((o_off + ln) * 128 + ks * 2 + hi * 16));
      s16x8 bf = *reinterpret_cast<const s16x8*>(ldsB + swz((t_off + ln) * 128 + ks * 2 + hi * 16));
      acc = __builtin_amdgcn_mfma_f32_32x32x16_bf16(af, bf, acc, 0, 0, 0);
    }
    __syncthreads();
  }

  size_t ybase = ((size_t)bp * 256 + o0) * 1024 + t0;
  float gs[4] = {0.f, 0.f, 0.f, 0.f}, gs2[4] = {0.f, 0.f, 0.f, 0.f};
#pragma unroll
  for (int r = 0; r < 16; ++r) {
    int o = o_off + (r & 3) + 8 * (r >> 2) + 4 * hi;
    float y = acc[r] + bias[o0 + o];
    Y[ybase + (size_t)o * 1024 + t_off + ln] = y;
    gs[r >> 2] += y;
    gs2[r >> 2] += y * y;
  }
#pragma unroll
  for (int off = 32; off > 0; off >>= 1) {
#pragma unroll
    for (int g2 = 0; g2 < 4; ++g2) {
      gs[g2]  += __shfl_xor(gs[g2], off);
      gs2[g2] += __shfl_xor(gs2[g2], off);
    }
  }
  float* lf = reinterpret_cast<float*>(lds);
  if ((tid & 63) == 0) {
#pragma unroll
    for (int g2 = 0; g2 < 4; ++g2) {
      lf[w * 8 + g2 * 2]     = gs[g2];
      lf[w * 8 + g2 * 2 + 1] = gs2[g2];
    }
  }
  __syncthreads();
  if (tid < 16) {
    int gl = tid >> 1, sidx = tid & 1;
    int wa = (gl < 4) ? 0 : 2;
    float v = lf[wa * 8 + (gl & 3) * 2 + sidx] +
              lf[(wa + 1) * 8 + (gl & 3) * 2 + sidx];
    int gg = bp * 32 + blockIdx.y * 8 + gl;
    pm_part[(gg * 16 + blockIdx.x) * 2 + sidx] = v;
  }
}

// out = GN(query + up4(0.25*(mb - qll))) + query; stats in-prologue.
__global__ __launch_bounds__(256) void idwt_gn_kernel(const float* __restrict__ mb,
    const unsigned short* __restrict__ qll, const float* __restrict__ query,
    const float* __restrict__ pm_part, const float* __restrict__ partial,
    const float* __restrict__ gamma, const float* __restrict__ beta,
    float* __restrict__ out) {
  int bc = blockIdx.x >> 2;
  int c = bc & 255;
  int g = (bc >> 8) * 32 + (c >> 3);

  __shared__ float sstat[2];
  if (threadIdx.x < 64) {
    int l = threadIdx.x;
    float s = 0.f, s2 = 0.f;
    if (l < 16) {
      float2 pp = *reinterpret_cast<const float2*>(pm_part + (g * 16 + l) * 2);
      s = pp.x; s2 = pp.y;
    } else if (l < 48) {
      int q = l - 16;
      int blk = (((g >> 5) * 256 + (g & 31) * 8 + (q >> 2)) << 2) + (q & 3);
      s2 = partial[blk];
    }
#pragma unroll
    for (int off = 32; off > 0; off >>= 1) {
      s  += __shfl_xor(s, off);
      s2 += __shfl_xor(s2, off);
    }
    if (l == 0) {
      float mean = 4.f * s * (1.f / 131072.f);
      float ex2  = s2 * (1.f / 131072.f);
      sstat[0] = mean;
      sstat[1] = rsqrtf(ex2 - mean * mean + 1e-5f);
    }
  }
  __syncthreads();
  float mean = sstat[0], rstd = sstat[1];

  int idx = blockIdx.x * 256 + threadIdx.x;
  int t  = idx & 1023;
  int i = t >> 5, j = t & 31;
  float a_s = rstd * gamma[c];
  float be  = beta[c];
  float delta = 0.25f * (mb[idx] - bflo((unsigned)qll[idx]));
  float k1 = 1.f + a_s;
  float k2 = (delta - mean) * a_s + be;
  const float* qp = query + (size_t)bc * 16384;
  float* op = out + (size_t)bc * 16384;
#pragma unroll
  for (int rr = 0; rr < 4; ++rr) {
    int off = (4 * i + rr) * 128 + 4 * j;
    float4 q = *reinterpret_cast<const float4*>(qp + off);
    float4 o;
    o.x = q.x * k1 + k2;
    o.y = q.y * k1 + k2;
    o.z = q.z * k1 + k2;
    o.w = q.w * k1 + k2;
    *reinterpret_cast<float4*>(op + off) = o;
  }
}

extern "C" void kernel_launch(void* const* d_in, const int* in_sizes, int n_in,
                              void* d_out, int out_size, void* d_ws, size_t ws_size,
                              hipStream_t stream) {
  const float* query = (const float*)d_in[0];
  const float* kvm   = (const float*)d_in[1];
  // d_in[2] = value_multi: unused by the reference
  const float* Wq = (const float*)d_in[3];
  const float* bq = (const float*)d_in[4];
  const float* Wk = (const float*)d_in[5];
  const float* bk = (const float*)d_in[6];
  const float* Wv = (const float*)d_in[7];
  const float* bv = (const float*)d_in[8];
  const float* Wp = (const float*)d_in[9];
  const float* bp = (const float*)d_in[10];
  const float* gamma = (const float*)d_in[11];
  const float* beta  = (const float*)d_in[12];
  float* out = (float*)d_out;
  float* ws  = (float*)d_ws;

  if (ws_size < (size_t)4198400 * 4) return;  // insufficient scratch

  unsigned short* qll  = (unsigned short*)ws;            // 524288 us
  unsigned*       qbp  = (unsigned*)(ws + 262144);       // 262144 u32
  unsigned*       kbp  = (unsigned*)(ws + 524288);       // 1048576 u32
  unsigned short* vb   = (unsigned short*)(ws + 1572864);// 2097152 us
  unsigned*       aop  = (unsigned*)(ws + 2621440);      // 1048576 u32
  float*          mb   = ws + 3670016;                   // 524288
  float*       partial = ws + 4194304;                   // 2048
  float*       pm_part = partial + 2048;                 // 2048

  kvconv_qdwt_kernel<<<2304, 256, 0, stream>>>(
      kvm, query, Wk, bk, Wv, bv, kbp, vb, qll, partial);

  conv_q_kernel<<<dim3(16, 4, 2), 256, 0, stream>>>(qll, Wq, bq, qbp);

  attn_mfma_kernel<<<512, 256, 0, stream>>>(qbp, kbp, vb, aop);

  conv_pm_kernel<<<dim3(16, 4, 2), 256, 0, stream>>>(aop, Wp, bp, mb, pm_part);

  idwt_gn_kernel<<<2048, 256, 0, stream>>>(mb, qll, query, pm_part, partial,
                                           gamma, beta, out);
}

// Round 10
// 90.795 us; speedup vs baseline: 1.3164x; 1.3164x over previous
//
#include <hip/hip_runtime.h>

// B=2, N=4, C=256, H=W=128, J=2, heads=8, hd=32, T=1024
// Algebra: idwt linear + Haar orthonormal =>
//   out_full = query + upsample4(0.25*(mb - qll))
//   sum(out) = 4*sum(mb); sum(out^2) = sum(query^2) + sum(mb^2) - sum(qll^2)
// GN stats assembled from register-level partials (no stats kernel):
//   dwt emits partial[qblock] = sum(q^2) - sum(qll_bf16^2)
//   conv_pm emits pm_part[group][t_tile] = (sum mb, sum mb^2)
//   idwt_gn reduces ~48 scalars per block in its prologue.
// NOTE (round-8 lesson): do NOT fuse the kvm stream into the K/V GEMM —
// 256 blocks cannot hide HBM latency for a 128 MB stream (measured 851 GB/s).
// The separate 8192-block dwt pass streams at ~7 TB/s.
// ws (float units): qll(bf16) 262144 | kvll(bf16) 1048576 | qbp(u32) 262144 |
//   kbp(u32) 1048576 | vb(bf16) 1048576 | aop(u32) 1048576 | mb 524288 |
//   partial 2048 | pm_part 2048

typedef float f32x16 __attribute__((ext_vector_type(16)));
typedef short s16x8 __attribute__((ext_vector_type(8)));

static __device__ __forceinline__ unsigned f2bf_bits(float x) {
  unsigned u = __float_as_uint(x);
  return (u + 0x7fffu + ((u >> 16) & 1u)) >> 16;
}
static __device__ __forceinline__ unsigned pack2(float a, float b) {
  return f2bf_bits(a) | (f2bf_bits(b) << 16);
}
static __device__ __forceinline__ float bflo(unsigned u) {
  return __uint_as_float(u << 16);
}
static __device__ __forceinline__ float bfhi(unsigned u) {
  return __uint_as_float(u & 0xffff0000u);
}
// XOR-swizzle for 128B-row LDS tiles: slot bits [6:4] ^= row bits [9:7]
static __device__ __forceinline__ int swz(int byte) {
  return byte ^ (((byte >> 7) & 7) << 4);
}

// Merged DWT: blocks [0,2048) = query (ll2 + partial = sum(q^2)-sum(qll^2));
// blocks [2048,10240) = kv ll2.
__global__ __launch_bounds__(256) void dwt_kernel(const float* __restrict__ query,
    const float* __restrict__ kvm, unsigned short* __restrict__ qll,
    unsigned short* __restrict__ kvll, float* __restrict__ partial) {
  int bid = blockIdx.x;
  if (bid < 2048) {
    int idx = bid * 256 + threadIdx.x;     // < 524288
    int bc = idx >> 10;
    int t  = idx & 1023;
    int i = t >> 5, j = t & 31;
    const float* xp = query + (size_t)bc * 16384;
    float s = 0.f, e = 0.f;
#pragma unroll
    for (int rr = 0; rr < 4; ++rr) {
      float4 v = *reinterpret_cast<const float4*>(xp + (4 * i + rr) * 128 + 4 * j);
      s += (v.x + v.y) + (v.z + v.w);
      e += (v.x * v.x + v.y * v.y) + (v.z * v.z + v.w * v.w);
    }
    unsigned bits = f2bf_bits(0.25f * s);
    qll[idx] = (unsigned short)bits;
    float qv = __uint_as_float(bits << 16);
    e -= qv * qv;
#pragma unroll
    for (int o = 32; o > 0; o >>= 1) e += __shfl_xor(e, o);
    __shared__ float red[4];
    if ((threadIdx.x & 63) == 0) red[threadIdx.x >> 6] = e;
    __syncthreads();
    if (threadIdx.x == 0)
      partial[bid] = (red[0] + red[1]) + (red[2] + red[3]);
  } else {
    int idx = (bid - 2048) * 256 + threadIdx.x;   // < 2097152
    int bc = idx >> 10;      // j*256 + c
    int t  = idx & 1023;
    int i = t >> 5, j2 = t & 31;
    int jj = bc >> 8, c = bc & 255;
    int n = jj >> 1, b = jj & 1;
    const float* xp = kvm + ((size_t)(b * 4 + n) * 256 + c) * 16384;
    float s = 0.f;
#pragma unroll
    for (int rr = 0; rr < 4; ++rr) {
      float4 v = *reinterpret_cast<const float4*>(xp + (4 * i + rr) * 128 + 4 * j2);
      s += (v.x + v.y) + (v.z + v.w);
    }
    kvll[idx] = (unsigned short)f2bf_bits(0.25f * s);
  }
}

// --- conv staging helpers ---------------------------------------------
static __device__ __forceinline__ void stage_w(const float* __restrict__ Wm,
    char* ldsA, int o0, int k0, int oA, int kqA, float sc) {
  const float* wp = Wm + (size_t)(o0 + oA) * 256 + k0 + kqA;
  float4 w0 = *reinterpret_cast<const float4*>(wp);
  float4 w1 = *reinterpret_cast<const float4*>(wp + 4);
  float4 w2 = *reinterpret_cast<const float4*>(wp + 8);
  float4 w3 = *reinterpret_cast<const float4*>(wp + 12);
  union { s16x8 v; unsigned u[4]; } a0, a1;
  a0.u[0] = pack2(sc * w0.x, sc * w0.y); a0.u[1] = pack2(sc * w0.z, sc * w0.w);
  a0.u[2] = pack2(sc * w1.x, sc * w1.y); a0.u[3] = pack2(sc * w1.z, sc * w1.w);
  a1.u[0] = pack2(sc * w2.x, sc * w2.y); a1.u[1] = pack2(sc * w2.z, sc * w2.w);
  a1.u[2] = pack2(sc * w3.x, sc * w3.y); a1.u[3] = pack2(sc * w3.z, sc * w3.w);
  int byte0 = oA * 128 + kqA * 2;
  *reinterpret_cast<s16x8*>(ldsA + swz(byte0))      = a0.v;
  *reinterpret_cast<s16x8*>(ldsA + swz(byte0 + 16)) = a1.v;
}

// X is bf16 [c][t] (ushort); pack k-pairs into u32.
static __device__ __forceinline__ void stage_x_bf(const unsigned short* __restrict__ Xp,
    char* ldsB, int k0, int t0, int tB, int kg0) {
#pragma unroll
  for (int rep = 0; rep < 2; ++rep) {
    int kg = kg0 + rep * 4;
    const unsigned short* xp = Xp + (size_t)(k0 + kg * 8) * 1024 + t0 + tB;
    union { s16x8 v; unsigned u[4]; } b;
#pragma unroll
    for (int e2 = 0; e2 < 4; ++e2) {
      unsigned lo = xp[(size_t)(2 * e2) * 1024];
      unsigned hi2 = xp[(size_t)(2 * e2 + 1) * 1024];
      b.u[e2] = lo | (hi2 << 16);
    }
    *reinterpret_cast<s16x8*>(ldsB + swz(tB * 128 + kg * 16)) = b.v;
  }
}

// A is paired-bf16 [cpair][t] (u32); mean over 4 j-slices (stride 131072 u32).
static __device__ __forceinline__ void stage_x_m4p(const unsigned* __restrict__ Ap,
    char* ldsB, int k0, int t0, int tB, int kg0) {
#pragma unroll
  for (int rep = 0; rep < 2; ++rep) {
    int kg = kg0 + rep * 4;
    const unsigned* xp = Ap + (size_t)(k0 / 2 + kg * 4) * 1024 + t0 + tB;
    union { s16x8 v; unsigned u[4]; } b;
#pragma unroll
    for (int e2 = 0; e2 < 4; ++e2) {
      unsigned a0 = xp[(size_t)e2 * 1024];
      unsigned a1 = xp[(size_t)e2 * 1024 + 131072];
      unsigned a2 = xp[(size_t)e2 * 1024 + 262144];
      unsigned a3 = xp[(size_t)e2 * 1024 + 393216];
      float lo = 0.25f * ((bflo(a0) + bflo(a1)) + (bflo(a2) + bflo(a3)));
      float hi2 = 0.25f * ((bfhi(a0) + bfhi(a1)) + (bfhi(a2) + bfhi(a3)));
      b.u[e2] = pack2(lo, hi2);
    }
    *reinterpret_cast<s16x8*>(ldsB + swz(tB * 128 + kg * 16)) = b.v;
  }
}

// ---------------------------------------------------------------------------
// Fused QKV conv: z<2 -> q (scaled Wq, paired out qbp); z>=2 -> kv dual.
// ---------------------------------------------------------------------------
__global__ __launch_bounds__(256) void conv_qkv_kernel(
    const unsigned short* __restrict__ qll, const unsigned short* __restrict__ kvll,
    const float* __restrict__ Wq, const float* __restrict__ bq,
    const float* __restrict__ Wk, const float* __restrict__ bk,
    const float* __restrict__ Wv, const float* __restrict__ bv,
    unsigned* __restrict__ qbp, unsigned* __restrict__ kbp,
    unsigned short* __restrict__ vb) {
  const int tid = threadIdx.x;
  const int hi = (tid >> 5) & 1;
  const int ln = tid & 31;
  const int w = tid >> 6;
  const int o_off = (w >> 1) * 32;
  const int t_off = (w & 1) * 32;
  const int t0 = blockIdx.x * 64;
  const int o0 = blockIdx.y * 64;
  const int z = blockIdx.z;

  __shared__ __align__(16) char lds[24576];
  char* ldsA  = lds;
  char* ldsA2 = lds + 8192;
  char* ldsB  = lds + 16384;

  const int oA = tid >> 2;
  const int kqA = (tid & 3) * 16;
  const int tB = tid & 63;
  const int kg0 = tid >> 6;

  if (z < 2) {
    const float S = 0.17677669529663687f;   // hd^-0.5 folded into Wq, bq
    const unsigned short* Xp = qll + (size_t)z * 262144;
    f32x16 acc;
#pragma unroll
    for (int r = 0; r < 16; ++r) acc[r] = 0.f;
    for (int kk = 0; kk < 4; ++kk) {
      const int k0 = kk * 64;
      stage_w(Wq, ldsA, o0, k0, oA, kqA, S);
      stage_x_bf(Xp, ldsB, k0, t0, tB, kg0);
      __syncthreads();
#pragma unroll
      for (int ks = 0; ks < 64; ks += 16) {
        s16x8 af = *reinterpret_cast<const s16x8*>(ldsA + swz((o_off + ln) * 128 + ks * 2 + hi * 16));
        s16x8 bf = *reinterpret_cast<const s16x8*>(ldsB + swz((t_off + ln) * 128 + ks * 2 + hi * 16));
        acc = __builtin_amdgcn_mfma_f32_32x32x16_bf16(af, bf, acc, 0, 0, 0);
      }
      __syncthreads();
    }
    unsigned* Yp = qbp + (size_t)z * 131072;
#pragma unroll
    for (int r = 0; r < 16; r += 2) {
      int o = o_off + (r & 3) + 8 * (r >> 2) + 4 * hi;    // even
      float b0 = S * bq[o0 + o], b1 = S * bq[o0 + o + 1];
      Yp[(size_t)((o0 + o) >> 1) * 1024 + t0 + t_off + ln] =
          pack2(acc[r] + b0, acc[r + 1] + b1);
    }
  } else {
    const int jj = z - 2;
    const unsigned short* Xp = kvll + (size_t)jj * 262144;
    f32x16 acck, accv;
#pragma unroll
    for (int r = 0; r < 16; ++r) { acck[r] = 0.f; accv[r] = 0.f; }
    for (int kk = 0; kk < 4; ++kk) {
      const int k0 = kk * 64;
      stage_w(Wk, ldsA,  o0, k0, oA, kqA, 1.f);
      stage_w(Wv, ldsA2, o0, k0, oA, kqA, 1.f);
      stage_x_bf(Xp, ldsB, k0, t0, tB, kg0);
      __syncthreads();
#pragma unroll
      for (int ks = 0; ks < 64; ks += 16) {
        s16x8 bf  = *reinterpret_cast<const s16x8*>(ldsB  + swz((t_off + ln) * 128 + ks * 2 + hi * 16));
        s16x8 afk = *reinterpret_cast<const s16x8*>(ldsA  + swz((o_off + ln) * 128 + ks * 2 + hi * 16));
        s16x8 afv = *reinterpret_cast<const s16x8*>(ldsA2 + swz((o_off + ln) * 128 + ks * 2 + hi * 16));
        acck = __builtin_amdgcn_mfma_f32_32x32x16_bf16(afk, bf, acck, 0, 0, 0);
        accv = __builtin_amdgcn_mfma_f32_32x32x16_bf16(afv, bf, accv, 0, 0, 0);
      }
      __syncthreads();
    }
    unsigned* Yk = kbp + (size_t)jj * 131072;
    unsigned short* Yv = vb + (size_t)jj * 262144;
#pragma unroll
    for (int r = 0; r < 16; r += 2) {
      int o = o_off + (r & 3) + 8 * (r >> 2) + 4 * hi;
      Yk[(size_t)((o0 + o) >> 1) * 1024 + t0 + t_off + ln] =
          pack2(acck[r] + bk[o0 + o], acck[r + 1] + bk[o0 + o + 1]);
    }
#pragma unroll
    for (int r = 0; r < 16; ++r) {
      int o = o_off + (r & 3) + 8 * (r >> 2) + 4 * hi;
      Yv[(size_t)o * 1024 + t0 + t_off + ln] =
          (unsigned short)f2bf_bits(accv[r] + bv[o0 + o]);
    }
  }
}

// ---------------------------------------------------------------------------
// MFMA flash attention (pre-paired bf16 inputs, __expf).
// ---------------------------------------------------------------------------
__global__ __launch_bounds__(256) void attn_mfma_kernel(
    const unsigned* __restrict__ qbp, const unsigned* __restrict__ kbp,
    const unsigned short* __restrict__ vb, unsigned* __restrict__ aop) {
  const int tid = threadIdx.x;
  const int w   = tid >> 6;
  const int hi  = (tid >> 5) & 1;
  const int ln  = tid & 31;
  const int jh  = blockIdx.x >> 3;
  const int qg  = blockIdx.x & 7;
  const int qbase = (qg * 4 + w) * 32;
  const int j = jh >> 3, h = jh & 7;
  const unsigned* qp = qbp + (size_t)((j & 1) * 8 + h) * 16384;
  const unsigned* kp = kbp + (size_t)jh * 16384;
  const unsigned short* vp = vb + (size_t)jh * 32768;

  __shared__ unsigned KpL[2][544];
  __shared__ unsigned VpL[2][544];
  __shared__ float tileT[4][1056];

  const int sdp = tid >> 5;   // 0..7
  const int st  = tid & 31;
  const int svd = tid >> 4;   // 0..15
  const int svt = tid & 15;

  s16x8 Qf[2];
#pragma unroll
  for (int c = 0; c < 2; ++c) {
    union { s16x8 v; unsigned u[4]; } u;
#pragma unroll
    for (int e2 = 0; e2 < 4; ++e2)
      u.u[e2] = qp[(size_t)(c * 8 + hi * 4 + e2) * 1024 + qbase + ln];
    Qf[c] = u.v;
  }

  f32x16 acc;
#pragma unroll
  for (int r = 0; r < 16; ++r) acc[r] = 0.f;
  float m = -1e30f, lsum = 0.f;

  {
    KpL[0][st * 17 + sdp]     = kp[(size_t)sdp * 1024 + st];
    KpL[0][st * 17 + sdp + 8] = kp[(size_t)(sdp + 8) * 1024 + st];
    VpL[0][svd * 17 + svt] =
        *reinterpret_cast<const unsigned*>(vp + (size_t)svd * 1024 + 2 * svt);
    VpL[0][(svd + 16) * 17 + svt] =
        *reinterpret_cast<const unsigned*>(vp + (size_t)(svd + 16) * 1024 + 2 * svt);
  }
  __syncthreads();

  for (int tile = 0; tile < 32; ++tile) {
    const int cur = tile & 1;
    unsigned nk0 = 0, nk1 = 0, nv0 = 0, nv1 = 0;
    if (tile < 31) {
      const int kn = (tile + 1) * 32;
      nk0 = kp[(size_t)sdp * 1024 + kn + st];
      nk1 = kp[(size_t)(sdp + 8) * 1024 + kn + st];
      nv0 = *reinterpret_cast<const unsigned*>(vp + (size_t)svd * 1024 + kn + 2 * svt);
      nv1 = *reinterpret_cast<const unsigned*>(vp + (size_t)(svd + 16) * 1024 + kn + 2 * svt);
    }

    s16x8 Kf[2];
#pragma unroll
    for (int c = 0; c < 2; ++c) {
      union { s16x8 v; unsigned u[4]; } u;
#pragma unroll
      for (int e = 0; e < 4; ++e)
        u.u[e] = KpL[cur][ln * 17 + c * 8 + hi * 4 + e];
      Kf[c] = u.v;
    }
    f32x16 S;
#pragma unroll
    for (int r = 0; r < 16; ++r) S[r] = 0.f;
    S = __builtin_amdgcn_mfma_f32_32x32x16_bf16(Kf[0], Qf[0], S, 0, 0, 0);
    S = __builtin_amdgcn_mfma_f32_32x32x16_bf16(Kf[1], Qf[1], S, 0, 0, 0);

    float tmax = S[0];
#pragma unroll
    for (int r = 1; r < 16; ++r) tmax = fmaxf(tmax, S[r]);
    tmax = fmaxf(tmax, __shfl_xor(tmax, 32));
    if (__any(tmax > m + 6.f)) {
      float nm = fmaxf(m, tmax);
      float f  = __expf(m - nm);
      m = nm;
      lsum *= f;
      int fi = __float_as_int(f);
#pragma unroll
      for (int r = 0; r < 16; ++r) {
        int row = (r & 3) + 8 * (r >> 2) + 4 * hi;
        float fr = __int_as_float(__builtin_amdgcn_ds_bpermute(row * 4, fi));
        acc[r] *= fr;
      }
    }
    float p[16];
#pragma unroll
    for (int r = 0; r < 16; ++r) {
      p[r] = __expf(S[r] - m);
      lsum += p[r];
    }
    unsigned P[8];
#pragma unroll
    for (int i = 0; i < 8; ++i) P[i] = pack2(p[2 * i], p[2 * i + 1]);

#pragma unroll
    for (int c = 0; c < 2; ++c) {
      unsigned p0 = P[4 * c + 0], p1 = P[4 * c + 1];
      unsigned p2 = P[4 * c + 2], p3 = P[4 * c + 3];
      unsigned s0 = (unsigned)__shfl_xor((int)p0, 32);
      unsigned s1 = (unsigned)__shfl_xor((int)p1, 32);
      unsigned s2 = (unsigned)__shfl_xor((int)p2, 32);
      unsigned s3 = (unsigned)__shfl_xor((int)p3, 32);
      union { s16x8 v; unsigned u[4]; } pa;
      pa.u[0] = hi ? s2 : p0;
      pa.u[1] = hi ? s3 : p1;
      pa.u[2] = hi ? p2 : s0;
      pa.u[3] = hi ? p3 : s1;
      union { s16x8 v; unsigned u[4]; } vf;
#pragma unroll
      for (int e = 0; e < 4; ++e)
        vf.u[e] = VpL[cur][ln * 17 + c * 8 + hi * 4 + e];
      acc = __builtin_amdgcn_mfma_f32_32x32x16_bf16(pa.v, vf.v, acc, 0, 0, 0);
    }

    if (tile < 31) {
      const int nxt = cur ^ 1;
      KpL[nxt][st * 17 + sdp]     = nk0;
      KpL[nxt][st * 17 + sdp + 8] = nk1;
      VpL[nxt][svd * 17 + svt]        = nv0;
      VpL[nxt][(svd + 16) * 17 + svt] = nv1;
    }
    __syncthreads();
  }

  float ltot = lsum + __shfl_xor(lsum, 32);
  float inv  = 1.f / ltot;

  float* tw = tileT[w];
#pragma unroll
  for (int r = 0; r < 16; ++r) {
    int row = (r & 3) + 8 * (r >> 2) + 4 * hi;
    tw[row * 33 + ln] = acc[r];
  }
  __syncthreads();
  unsigned* aw = aop + (size_t)jh * 16384;
#pragma unroll
  for (int pass = 0; pass < 8; ++pass) {
    int dp = pass * 2 + hi;
    float v0 = tw[ln * 33 + 2 * dp] * inv;
    float v1 = tw[ln * 33 + 2 * dp + 1] * inv;
    aw[(size_t)dp * 1024 + qbase + ln] = pack2(v0, v1);
  }
}

// ---------------------------------------------------------------------------
// P-conv with fused mean over 4 j-slices; emits per-(group, t-tile) GN
// partials (sum, sum^2) from registers. Deterministic slots, no atomics.
// ---------------------------------------------------------------------------
__global__ __launch_bounds__(256) void conv_pm_kernel(const unsigned* __restrict__ aop,
    const float* __restrict__ Wm, const float* __restrict__ bias,
    float* __restrict__ Y, float* __restrict__ pm_part) {
  const int tid = threadIdx.x;
  const int hi = (tid >> 5) & 1;
  const int ln = tid & 31;
  const int w = tid >> 6;
  const int o_off = (w >> 1) * 32;
  const int t_off = (w & 1) * 32;
  const int t0 = blockIdx.x * 64;
  const int o0 = blockIdx.y * 64;
  const int bp = blockIdx.z;
  const unsigned* Ap = aop + (size_t)bp * 524288;

  __shared__ __align__(16) char lds[16384];
  char* ldsA = lds;
  char* ldsB = lds + 8192;

  f32x16 acc;
#pragma unroll
  for (int r = 0; r < 16; ++r) acc[r] = 0.f;

  const int oA = tid >> 2;
  const int kqA = (tid & 3) * 16;
  const int tB = tid & 63;
  const int kg0 = tid >> 6;

  for (int kk = 0; kk < 4; ++kk) {
    const int k0 = kk * 64;
    stage_w(Wm, ldsA, o0, k0, oA, kqA, 1.f);
    stage_x_m4p(Ap, ldsB, k0, t0, tB, kg0);
    __syncthreads();
#pragma unroll
    for (int ks = 0; ks < 64; ks += 16) {
      s16x8 af = *reinterpret_cast<const s16x8*>(ldsA + swz((o_off + ln) * 128 + ks * 2 + hi * 16));
      s16x8 bf = *reinterpret_cast<const s16x8*>(ldsB + swz((t_off + ln) * 128 + ks * 2 + hi * 16));
      acc = __builtin_amdgcn_mfma_f32_32x32x16_bf16(af, bf, acc, 0, 0, 0);
    }
    __syncthreads();
  }

  size_t ybase = ((size_t)bp * 256 + o0) * 1024 + t0;
  // r>>2 selects the 8-channel group within this wave's o-range.
  float gs[4] = {0.f, 0.f, 0.f, 0.f}, gs2[4] = {0.f, 0.f, 0.f, 0.f};
#pragma unroll
  for (int r = 0; r < 16; ++r) {
    int o = o_off + (r & 3) + 8 * (r >> 2) + 4 * hi;
    float y = acc[r] + bias[o0 + o];
    Y[ybase + (size_t)o * 1024 + t_off + ln] = y;
    gs[r >> 2] += y;
    gs2[r >> 2] += y * y;
  }
  // wave butterfly reduce (64 lanes)
#pragma unroll
  for (int off = 32; off > 0; off >>= 1) {
#pragma unroll
    for (int g2 = 0; g2 < 4; ++g2) {
      gs[g2]  += __shfl_xor(gs[g2], off);
      gs2[g2] += __shfl_xor(gs2[g2], off);
    }
  }
  float* lf = reinterpret_cast<float*>(lds);
  if ((tid & 63) == 0) {
#pragma unroll
    for (int g2 = 0; g2 < 4; ++g2) {
      lf[w * 8 + g2 * 2]     = gs[g2];
      lf[w * 8 + g2 * 2 + 1] = gs2[g2];
    }
  }
  __syncthreads();
  if (tid < 16) {
    int gl = tid >> 1, sidx = tid & 1;
    int wa = (gl < 4) ? 0 : 2;   // waves 0,1 cover groups 0-3; waves 2,3 -> 4-7
    float v = lf[wa * 8 + (gl & 3) * 2 + sidx] +
              lf[(wa + 1) * 8 + (gl & 3) * 2 + sidx];
    int gg = bp * 32 + blockIdx.y * 8 + gl;
    pm_part[(gg * 16 + blockIdx.x) * 2 + sidx] = v;
  }
}

// out = GN(query + up4(0.25*(mb - qll))) + query; group stats computed
// in-prologue from pm_part (16x2) + dwt partial (32) scalars.
__global__ __launch_bounds__(256) void idwt_gn_kernel(const float* __restrict__ mb,
    const unsigned short* __restrict__ qll, const float* __restrict__ query,
    const float* __restrict__ pm_part, const float* __restrict__ partial,
    const float* __restrict__ gamma, const float* __restrict__ beta,
    float* __restrict__ out) {
  int bc = blockIdx.x >> 2;               // one bc per 4 blocks
  int c = bc & 255;
  int g = (bc >> 8) * 32 + (c >> 3);

  __shared__ float sstat[2];
  if (threadIdx.x < 64) {
    int l = threadIdx.x;
    float s = 0.f, s2 = 0.f;
    if (l < 16) {
      float2 pp = *reinterpret_cast<const float2*>(pm_part + (g * 16 + l) * 2);
      s = pp.x; s2 = pp.y;
    } else if (l < 48) {
      int q = l - 16;                     // cc = q>>2, quarter = q&3
      int blk = (((g >> 5) * 256 + (g & 31) * 8 + (q >> 2)) << 2) + (q & 3);
      s2 = partial[blk];
    }
#pragma unroll
    for (int off = 32; off > 0; off >>= 1) {
      s  += __shfl_xor(s, off);
      s2 += __shfl_xor(s2, off);
    }
    if (l == 0) {
      float mean = 4.f * s * (1.f / 131072.f);
      float ex2  = s2 * (1.f / 131072.f);
      sstat[0] = mean;
      sstat[1] = rsqrtf(ex2 - mean * mean + 1e-5f);
    }
  }
  __syncthreads();
  float mean = sstat[0], rstd = sstat[1];

  int idx = blockIdx.x * 256 + threadIdx.x;   // < 524288
  int t  = idx & 1023;
  int i = t >> 5, j = t & 31;
  float a_s = rstd * gamma[c];
  float be  = beta[c];
  float delta = 0.25f * (mb[idx] - bflo((unsigned)qll[idx]));
  float k1 = 1.f + a_s;
  float k2 = (delta - mean) * a_s + be;
  const float* qp = query + (size_t)bc * 16384;
  float* op = out + (size_t)bc * 16384;
#pragma unroll
  for (int rr = 0; rr < 4; ++rr) {
    int off = (4 * i + rr) * 128 + 4 * j;
    float4 q = *reinterpret_cast<const float4*>(qp + off);
    float4 o;
    o.x = q.x * k1 + k2;
    o.y = q.y * k1 + k2;
    o.z = q.z * k1 + k2;
    o.w = q.w * k1 + k2;
    *reinterpret_cast<float4*>(op + off) = o;
  }
}

extern "C" void kernel_launch(void* const* d_in, const int* in_sizes, int n_in,
                              void* d_out, int out_size, void* d_ws, size_t ws_size,
                              hipStream_t stream) {
  const float* query = (const float*)d_in[0];
  const float* kvm   = (const float*)d_in[1];
  // d_in[2] = value_multi: unused by the reference
  const float* Wq = (const float*)d_in[3];
  const float* bq = (const float*)d_in[4];
  const float* Wk = (const float*)d_in[5];
  const float* bk = (const float*)d_in[6];
  const float* Wv = (const float*)d_in[7];
  const float* bv = (const float*)d_in[8];
  const float* Wp = (const float*)d_in[9];
  const float* bp = (const float*)d_in[10];
  const float* gamma = (const float*)d_in[11];
  const float* beta  = (const float*)d_in[12];
  float* out = (float*)d_out;
  float* ws  = (float*)d_ws;

  if (ws_size < (size_t)5246976 * 4) return;  // insufficient scratch

  unsigned short* qll  = (unsigned short*)ws;            // 524288 us
  unsigned short* kvll = (unsigned short*)(ws + 262144); // 2097152 us
  unsigned*       qbp  = (unsigned*)(ws + 1310720);      // 262144 u32
  unsigned*       kbp  = (unsigned*)(ws + 1572864);      // 1048576 u32
  unsigned short* vb   = (unsigned short*)(ws + 2621440);// 2097152 us
  unsigned*       aop  = (unsigned*)(ws + 3670016);      // 1048576 u32
  float*          mb   = ws + 4718592;                   // 524288
  float*       partial = ws + 5242880;                   // 2048
  float*       pm_part = partial + 2048;                 // 2048

  dwt_kernel<<<10240, 256, 0, stream>>>(query, kvm, qll, kvll, partial);

  conv_qkv_kernel<<<dim3(16, 4, 10), 256, 0, stream>>>(
      qll, kvll, Wq, bq, Wk, bk, Wv, bv, qbp, kbp, vb);

  attn_mfma_kernel<<<512, 256, 0, stream>>>(qbp, kbp, vb, aop);

  conv_pm_kernel<<<dim3(16, 4, 2), 256, 0, stream>>>(aop, Wp, bp, mb, pm_part);

  idwt_gn_kernel<<<2048, 256, 0, stream>>>(mb, qll, query, pm_part, partial,
                                           gamma, beta, out);
}